// Round 1
// baseline (1487.316 us; speedup 1.0000x reference)
//
#include <hip/hip_runtime.h>

#define D 128

// out[i][j] = b[j]  (also overwrites the 0xAA poison)
__global__ __launch_bounds__(256) void init_out_kernel(float* __restrict__ out,
                                                       const float* __restrict__ b,
                                                       int total) {
  int t = blockIdx.x * 256 + threadIdx.x;
  if (t < total) out[t] = b[t & (D - 1)];
}

// y = x @ W^T   (bias NOT applied here — it must be added once, post-aggregation)
// Per wave: 8 nodes, lane j covers outputs j and j+64. W transposed in LDS.
__global__ __launch_bounds__(256, 2) void gemm_xwT_kernel(
    const float* __restrict__ x, const float* __restrict__ W,
    float* __restrict__ y, int N) {
  __shared__ float Wt[D * D];        // Wt[k*128 + j] = W[j*128 + k]
  __shared__ float Arow[4][8 * D];   // per-wave staging of 8 x-rows

  const int tid = threadIdx.x;
  // Stage W transposed. Global read coalesced; LDS write is bank-conflicted but
  // runs once per block (~4K cycles) — negligible vs main loop.
  for (int idx = tid; idx < D * D; idx += 256) {
    int j = idx >> 7;
    int k = idx & (D - 1);
    Wt[k * D + j] = W[idx];
  }
  __syncthreads();

  const int wave = tid >> 6;
  const int lane = tid & 63;
  const int gwave = blockIdx.x * 4 + wave;
  const int nwaves = gridDim.x * 4;
  const float4* x4 = (const float4*)x;

  for (int base = gwave * 8; base < N; base += nwaves * 8) {
    // Stage 8 rows (256 float4) into this wave's LDS slab.
    float4* dst4 = (float4*)(&Arow[wave][0]);
#pragma unroll
    for (int r = 0; r < 4; ++r) {
      int idx = r * 64 + lane;   // float4 index 0..255
      int e = idx >> 5;          // node within group (32 float4 per row)
      int q = idx & 31;
      int node = base + e;
      float4 v = make_float4(0.f, 0.f, 0.f, 0.f);
      if (node < N) v = x4[node * 32 + q];
      dst4[idx] = v;
    }
    // (same-wave LDS RAW — compiler inserts lgkmcnt waits; no barrier needed)

    float acc0[8], acc1[8];
#pragma unroll
    for (int e = 0; e < 8; ++e) { acc0[e] = 0.f; acc1[e] = 0.f; }

#pragma unroll 4
    for (int kq = 0; kq < 32; ++kq) {
      float w0[4], w1[4];
#pragma unroll
      for (int t4 = 0; t4 < 4; ++t4) {
        w0[t4] = Wt[(kq * 4 + t4) * D + lane];        // conflict-free
        w1[t4] = Wt[(kq * 4 + t4) * D + lane + 64];
      }
#pragma unroll
      for (int e = 0; e < 8; ++e) {
        float4 a = ((const float4*)(&Arow[wave][e * D]))[kq];  // broadcast read
        acc0[e] += a.x * w0[0] + a.y * w0[1] + a.z * w0[2] + a.w * w0[3];
        acc1[e] += a.x * w1[0] + a.y * w1[1] + a.z * w1[2] + a.w * w1[3];
      }
    }

#pragma unroll
    for (int e = 0; e < 8; ++e) {
      int node = base + e;
      if (node < N) {
        y[node * D + lane]      = acc0[e];
        y[node * D + lane + 64] = acc1[e];
      }
    }
  }
}

// out[row[e]][:] += w[e] * y[col[e]][:]   — one thread per (edge, 4-float chunk)
__global__ __launch_bounds__(256) void scatter_kernel(
    const float* __restrict__ y, const int* __restrict__ row,
    const int* __restrict__ col, const float* __restrict__ w,
    float* __restrict__ out, long long total) {
  long long t = (long long)blockIdx.x * 256 + threadIdx.x;
  if (t >= total) return;
  int e = (int)(t >> 5);
  int q = (int)(t & 31);
  int c = col[e];
  int r = row[e];
  float we = w[e];
  float4 v = ((const float4*)y)[c * 32 + q];   // 512B/edge contiguous gather
  float* dst = out + r * D + q * 4;
  atomicAdd(dst + 0, we * v.x);
  atomicAdd(dst + 1, we * v.y);
  atomicAdd(dst + 2, we * v.z);
  atomicAdd(dst + 3, we * v.w);
}

extern "C" void kernel_launch(void* const* d_in, const int* in_sizes, int n_in,
                              void* d_out, int out_size, void* d_ws, size_t ws_size,
                              hipStream_t stream) {
  const float* x    = (const float*)d_in[0];
  const int*   erow = (const int*)d_in[1];
  const int*   ecol = (const int*)d_in[2];
  const float* ew   = (const float*)d_in[3];
  const float* W    = (const float*)d_in[4];
  const float* b    = (const float*)d_in[5];
  float* out = (float*)d_out;
  float* y   = (float*)d_ws;   // N*128 floats = 25.6 MB scratch

  const int N = in_sizes[0] / D;
  const int E = in_sizes[1];
  const int total_out = N * D;

  // 1) out = b (broadcast)  — must precede scatter
  init_out_kernel<<<(total_out + 255) / 256, 256, 0, stream>>>(out, b, total_out);

  // 2) y = x @ W^T
  gemm_xwT_kernel<<<512, 256, 0, stream>>>(x, W, y, N);

  // 3) out[row] += w * y[col]
  long long total_sc = (long long)E * 32;
  int blocks = (int)((total_sc + 255) / 256);
  scatter_kernel<<<blocks, 256, 0, stream>>>(y, erow, ecol, ew, out, total_sc);
}

// Round 2
// 395.284 us; speedup vs baseline: 3.7626x; 3.7626x over previous
//
#include <hip/hip_runtime.h>

#define D 128

// ---------------- CSR build ----------------

__global__ __launch_bounds__(256) void zero_cnt_kernel(int* __restrict__ cnt, int N) {
  int t = blockIdx.x * 256 + threadIdx.x;
  if (t < N) cnt[t] = 0;
}

__global__ __launch_bounds__(256) void hist_kernel(const int* __restrict__ row,
                                                   int* __restrict__ cnt, int E) {
  int e = blockIdx.x * 256 + threadIdx.x;
  if (e < E) atomicAdd(&cnt[row[e]], 1);
}

// Single-block exclusive scan over cnt[0..N) -> rowptr[0..N], plus cur[] copy.
__global__ __launch_bounds__(1024) void scan_kernel(const int* __restrict__ cnt,
                                                    int* __restrict__ rowptr,
                                                    int* __restrict__ cur,
                                                    int N, int E) {
  __shared__ int partial[1024];
  const int t = threadIdx.x;
  const int chunk = (N + 1023) / 1024;
  const int begin = t * chunk;
  const int end = min(begin + chunk, N);
  int s = 0;
  for (int i = begin; i < end; ++i) s += cnt[i];
  partial[t] = s;
  __syncthreads();
  for (int off = 1; off < 1024; off <<= 1) {
    int v = 0;
    if (t >= off) v = partial[t - off];
    __syncthreads();
    if (t >= off) partial[t] += v;
    __syncthreads();
  }
  int run = (t == 0) ? 0 : partial[t - 1];
  for (int i = begin; i < end; ++i) {
    int c = cnt[i];
    rowptr[i] = run;
    cur[i] = run;
    run += c;
  }
  if (t == 0) rowptr[N] = E;
}

__global__ __launch_bounds__(256) void reorder_kernel(
    const int* __restrict__ row, const int* __restrict__ col,
    const float* __restrict__ w, int* __restrict__ cur,
    int* __restrict__ scol, float* __restrict__ sw, int E) {
  int e = blockIdx.x * 256 + threadIdx.x;
  if (e >= E) return;
  int r = row[e];
  int pos = atomicAdd(&cur[r], 1);
  scol[pos] = col[e];
  sw[pos] = w[e];
}

// ---------------- y = x @ W^T (no bias) ----------------

__global__ __launch_bounds__(256, 2) void gemm_xwT_kernel(
    const float* __restrict__ x, const float* __restrict__ W,
    float* __restrict__ y, int N) {
  __shared__ float Wt[D * D];        // Wt[k*128 + j] = W[j*128 + k]
  __shared__ float Arow[4][8 * D];   // per-wave staging of 8 x-rows

  const int tid = threadIdx.x;
  for (int idx = tid; idx < D * D; idx += 256) {
    int j = idx >> 7;
    int k = idx & (D - 1);
    Wt[k * D + j] = W[idx];
  }
  __syncthreads();

  const int wave = tid >> 6;
  const int lane = tid & 63;
  const int gwave = blockIdx.x * 4 + wave;
  const int nwaves = gridDim.x * 4;
  const float4* x4 = (const float4*)x;

  for (int base = gwave * 8; base < N; base += nwaves * 8) {
    float4* dst4 = (float4*)(&Arow[wave][0]);
#pragma unroll
    for (int r = 0; r < 4; ++r) {
      int idx = r * 64 + lane;
      int e = idx >> 5;
      int q = idx & 31;
      int node = base + e;
      float4 v = make_float4(0.f, 0.f, 0.f, 0.f);
      if (node < N) v = x4[node * 32 + q];
      dst4[idx] = v;
    }

    float acc0[8], acc1[8];
#pragma unroll
    for (int e = 0; e < 8; ++e) { acc0[e] = 0.f; acc1[e] = 0.f; }

#pragma unroll 4
    for (int kq = 0; kq < 32; ++kq) {
      float w0[4], w1[4];
#pragma unroll
      for (int t4 = 0; t4 < 4; ++t4) {
        w0[t4] = Wt[(kq * 4 + t4) * D + lane];
        w1[t4] = Wt[(kq * 4 + t4) * D + lane + 64];
      }
#pragma unroll
      for (int e = 0; e < 8; ++e) {
        float4 a = ((const float4*)(&Arow[wave][e * D]))[kq];
        acc0[e] += a.x * w0[0] + a.y * w0[1] + a.z * w0[2] + a.w * w0[3];
        acc1[e] += a.x * w1[0] + a.y * w1[1] + a.z * w1[2] + a.w * w1[3];
      }
    }

#pragma unroll
    for (int e = 0; e < 8; ++e) {
      int node = base + e;
      if (node < N) {
        y[node * D + lane]      = acc0[e];
        y[node * D + lane + 64] = acc1[e];
      }
    }
  }
}

// ---------------- gather aggregation: out[i] = b + sum_j w_j * y[col_j] ----------------
// One wave per node; lane holds float2 (cols 2*lane, 2*lane+1).

__global__ __launch_bounds__(256) void gather_agg_kernel(
    const float* __restrict__ y, const int* __restrict__ rowptr,
    const int* __restrict__ scol, const float* __restrict__ sw,
    const float* __restrict__ b, float* __restrict__ out, int N) {
  const int node = blockIdx.x * 4 + (threadIdx.x >> 6);
  const int lane = threadIdx.x & 63;
  if (node >= N) return;

  const float2* __restrict__ y2 = (const float2*)y;
  float2 acc = ((const float2*)b)[lane];

  const int s = rowptr[node];
  const int t = rowptr[node + 1];
#pragma unroll 4
  for (int j = s; j < t; ++j) {
    int c = scol[j];          // wave-uniform broadcast
    float wg = sw[j];
    float2 v = y2[c * 64 + lane];  // 512 B coalesced gather, L3-resident
    acc.x += wg * v.x;
    acc.y += wg * v.y;
  }
  ((float2*)out)[node * 64 + lane] = acc;
}

// ---------------- launch ----------------

extern "C" void kernel_launch(void* const* d_in, const int* in_sizes, int n_in,
                              void* d_out, int out_size, void* d_ws, size_t ws_size,
                              hipStream_t stream) {
  const float* x    = (const float*)d_in[0];
  const int*   erow = (const int*)d_in[1];
  const int*   ecol = (const int*)d_in[2];
  const float* ew   = (const float*)d_in[3];
  const float* W    = (const float*)d_in[4];
  const float* b    = (const float*)d_in[5];
  float* out = (float*)d_out;

  const int N = in_sizes[0] / D;
  const int E = in_sizes[1];

  // Workspace layout (4-byte units)
  char* ws = (char*)d_ws;
  float* y      = (float*)ws;                         // N*D floats  (25.6 MB)
  int*   cnt    = (int*)(ws + (size_t)N * D * 4);     // N ints
  int*   rowptr = cnt + N;                            // N+1 ints
  int*   cur    = rowptr + N + 1;                     // N ints
  int*   scol   = cur + N;                            // E ints
  float* sw     = (float*)(scol + E);                 // E floats

  const int eb = (E + 255) / 256;
  const int nb = (N + 255) / 256;

  zero_cnt_kernel<<<nb, 256, 0, stream>>>(cnt, N);
  hist_kernel<<<eb, 256, 0, stream>>>(erow, cnt, E);
  scan_kernel<<<1, 1024, 0, stream>>>(cnt, rowptr, cur, N, E);
  reorder_kernel<<<eb, 256, 0, stream>>>(erow, ecol, ew, cur, scol, sw, E);

  gemm_xwT_kernel<<<512, 256, 0, stream>>>(x, W, y, N);

  gather_agg_kernel<<<(N + 3) / 4, 256, 0, stream>>>(y, rowptr, scol, sw, b, out, N);
}

// Round 3
// 285.634 us; speedup vs baseline: 5.2071x; 1.3839x over previous
//
#include <hip/hip_runtime.h>

#define D 128

// ---------------- CSR build ----------------

// zero cnt[0..N) and total (one extra slot)
__global__ __launch_bounds__(256) void zero_cnt_kernel(int* __restrict__ cnt, int N) {
  int t = blockIdx.x * 256 + threadIdx.x;
  if (t < N + 1) cnt[t] = 0;
}

__global__ __launch_bounds__(256) void hist_kernel(const int* __restrict__ row,
                                                   int* __restrict__ cnt, int E) {
  int e = blockIdx.x * 256 + threadIdx.x;
  if (e < E) atomicAdd(&cnt[row[e]], 1);
}

// Unordered segment assignment: each block scans 2048 counts locally (LDS),
// grabs a global base with ONE atomicAdd, writes start[] and cur[].
// Segment order across blocks is arbitrary — gather only needs contiguity.
__global__ __launch_bounds__(256) void assign_starts_kernel(
    const int* __restrict__ cnt, int* __restrict__ start, int* __restrict__ cur,
    int* __restrict__ total, int N) {
  __shared__ int lds[256];
  __shared__ int base_sh;
  const int t = threadIdx.x;
  const int b0 = blockIdx.x * 2048;

  int c[8];
  int s = 0;
#pragma unroll
  for (int r = 0; r < 8; ++r) {
    int i = b0 + t * 8 + r;
    c[r] = (i < N) ? cnt[i] : 0;
    s += c[r];
  }
  lds[t] = s;
  __syncthreads();
  // inclusive scan over the 256 per-thread sums
  for (int off = 1; off < 256; off <<= 1) {
    int v = 0;
    if (t >= off) v = lds[t - off];
    __syncthreads();
    if (t >= off) lds[t] += v;
    __syncthreads();
  }
  if (t == 255) base_sh = atomicAdd(total, lds[255]);
  __syncthreads();

  int run = base_sh + (t == 0 ? 0 : lds[t - 1]);
#pragma unroll
  for (int r = 0; r < 8; ++r) {
    int i = b0 + t * 8 + r;
    if (i < N) { start[i] = run; cur[i] = run; }
    run += c[r];
  }
}

// swcol[pos] = (col, bits(weight)) — one 8B store per edge
__global__ __launch_bounds__(256) void reorder_kernel(
    const int* __restrict__ row, const int* __restrict__ col,
    const float* __restrict__ w, int* __restrict__ cur,
    int2* __restrict__ swcol, int E) {
  int e = blockIdx.x * 256 + threadIdx.x;
  if (e >= E) return;
  int pos = atomicAdd(&cur[row[e]], 1);
  swcol[pos] = make_int2(col[e], __float_as_int(w[e]));
}

// ---------------- y = x @ W^T (no bias) ----------------

__global__ __launch_bounds__(256, 2) void gemm_xwT_kernel(
    const float* __restrict__ x, const float* __restrict__ W,
    float* __restrict__ y, int N) {
  __shared__ float Wt[D * D];        // Wt[k*128 + j] = W[j*128 + k]
  __shared__ float Arow[4][8 * D];   // per-wave staging of 8 x-rows

  const int tid = threadIdx.x;
  for (int idx = tid; idx < D * D; idx += 256) {
    int j = idx >> 7;
    int k = idx & (D - 1);
    Wt[k * D + j] = W[idx];
  }
  __syncthreads();

  const int wave = tid >> 6;
  const int lane = tid & 63;
  const int gwave = blockIdx.x * 4 + wave;
  const int nwaves = gridDim.x * 4;
  const float4* x4 = (const float4*)x;

  for (int base = gwave * 8; base < N; base += nwaves * 8) {
    float4* dst4 = (float4*)(&Arow[wave][0]);
#pragma unroll
    for (int r = 0; r < 4; ++r) {
      int idx = r * 64 + lane;
      int e = idx >> 5;
      int q = idx & 31;
      int node = base + e;
      float4 v = make_float4(0.f, 0.f, 0.f, 0.f);
      if (node < N) v = x4[node * 32 + q];
      dst4[idx] = v;
    }

    float acc0[8], acc1[8];
#pragma unroll
    for (int e = 0; e < 8; ++e) { acc0[e] = 0.f; acc1[e] = 0.f; }

#pragma unroll 4
    for (int kq = 0; kq < 32; ++kq) {
      float w0[4], w1[4];
#pragma unroll
      for (int t4 = 0; t4 < 4; ++t4) {
        w0[t4] = Wt[(kq * 4 + t4) * D + lane];
        w1[t4] = Wt[(kq * 4 + t4) * D + lane + 64];
      }
#pragma unroll
      for (int e = 0; e < 8; ++e) {
        float4 a = ((const float4*)(&Arow[wave][e * D]))[kq];
        acc0[e] += a.x * w0[0] + a.y * w0[1] + a.z * w0[2] + a.w * w0[3];
        acc1[e] += a.x * w1[0] + a.y * w1[1] + a.z * w1[2] + a.w * w1[3];
      }
    }

#pragma unroll
    for (int e = 0; e < 8; ++e) {
      int node = base + e;
      if (node < N) {
        y[node * D + lane]      = acc0[e];
        y[node * D + lane + 64] = acc1[e];
      }
    }
  }
}

// ---------------- gather aggregation: out[i] = b + sum_j w_j * y[col_j] ----------------
// One wave per node; lane holds float2 (cols 2*lane, 2*lane+1).

__global__ __launch_bounds__(256) void gather_agg_kernel(
    const float* __restrict__ y, const int* __restrict__ start,
    const int* __restrict__ cnt, const int2* __restrict__ swcol,
    const float* __restrict__ b, float* __restrict__ out, int N) {
  const int node = blockIdx.x * 4 + (threadIdx.x >> 6);
  const int lane = threadIdx.x & 63;
  if (node >= N) return;

  const float2* __restrict__ y2 = (const float2*)y;
  float2 acc = ((const float2*)b)[lane];

  const int s = start[node];
  const int t = s + cnt[node];
#pragma unroll 4
  for (int j = s; j < t; ++j) {
    int2 cw = swcol[j];                 // wave-uniform 8B broadcast
    float wg = __int_as_float(cw.y);
    float2 v = y2[cw.x * 64 + lane];    // 512 B coalesced gather, L3-resident
    acc.x += wg * v.x;
    acc.y += wg * v.y;
  }
  ((float2*)out)[node * 64 + lane] = acc;
}

// ---------------- launch ----------------

extern "C" void kernel_launch(void* const* d_in, const int* in_sizes, int n_in,
                              void* d_out, int out_size, void* d_ws, size_t ws_size,
                              hipStream_t stream) {
  const float* x    = (const float*)d_in[0];
  const int*   erow = (const int*)d_in[1];
  const int*   ecol = (const int*)d_in[2];
  const float* ew   = (const float*)d_in[3];
  const float* W    = (const float*)d_in[4];
  const float* b    = (const float*)d_in[5];
  float* out = (float*)d_out;

  const int N = in_sizes[0] / D;
  const int E = in_sizes[1];

  // Workspace layout (8B-aligned segments)
  char* ws = (char*)d_ws;
  float* y      = (float*)ws;                               // N*D floats (25.6 MB)
  int2*  swcol  = (int2*)(ws + (size_t)N * D * 4);          // E int2 (6.4 MB), 8B-aligned
  int*   cnt    = (int*)(swcol + E);                        // N ints
  int*   total  = cnt + N;                                  // 1 int
  int*   start  = total + 1;                                // N ints
  int*   cur    = start + N;                                // N ints

  const int eb = (E + 255) / 256;
  const int nb = (N + 1 + 255) / 256;

  zero_cnt_kernel<<<nb, 256, 0, stream>>>(cnt, N);          // zeroes cnt + total
  hist_kernel<<<eb, 256, 0, stream>>>(erow, cnt, E);
  assign_starts_kernel<<<(N + 2047) / 2048, 256, 0, stream>>>(cnt, start, cur, total, N);
  reorder_kernel<<<eb, 256, 0, stream>>>(erow, ecol, ew, cur, swcol, E);

  gemm_xwT_kernel<<<512, 256, 0, stream>>>(x, W, y, N);

  gather_agg_kernel<<<(N + 3) / 4, 256, 0, stream>>>(y, start, cnt, swcol, b, out, N);
}

// Round 4
// 231.242 us; speedup vs baseline: 6.4319x; 1.2352x over previous
//
#include <hip/hip_runtime.h>

#define D 128

typedef __attribute__((ext_vector_type(8))) short bf16x8;  // 8 bf16 = 4 VGPRs
typedef __attribute__((ext_vector_type(4))) float f32x4;

__device__ __forceinline__ short f2bf_rne(float f) {
  unsigned u = __float_as_uint(f);
  unsigned r = u + 0x7fffu + ((u >> 16) & 1u);   // round-to-nearest-even
  return (short)(r >> 16);
}

__device__ __forceinline__ bf16x8 pack_bf16x8(float4 a, float4 b) {
  bf16x8 h;
  h[0] = f2bf_rne(a.x); h[1] = f2bf_rne(a.y);
  h[2] = f2bf_rne(a.z); h[3] = f2bf_rne(a.w);
  h[4] = f2bf_rne(b.x); h[5] = f2bf_rne(b.y);
  h[6] = f2bf_rne(b.z); h[7] = f2bf_rne(b.w);
  return h;
}

// ---------------- CSR build ----------------

__global__ __launch_bounds__(256) void zero_cnt_kernel(int* __restrict__ cnt, int N) {
  int t = blockIdx.x * 256 + threadIdx.x;
  if (t < N + 1) cnt[t] = 0;
}

__global__ __launch_bounds__(256) void hist_kernel(const int* __restrict__ row,
                                                   int* __restrict__ cnt, int E) {
  int e = blockIdx.x * 256 + threadIdx.x;
  if (e < E) atomicAdd(&cnt[row[e]], 1);
}

// Unordered segment assignment: block-local scan + one global atomicAdd.
__global__ __launch_bounds__(256) void assign_starts_kernel(
    const int* __restrict__ cnt, int* __restrict__ start, int* __restrict__ cur,
    int* __restrict__ total, int N) {
  __shared__ int lds[256];
  __shared__ int base_sh;
  const int t = threadIdx.x;
  const int b0 = blockIdx.x * 2048;

  int c[8];
  int s = 0;
#pragma unroll
  for (int r = 0; r < 8; ++r) {
    int i = b0 + t * 8 + r;
    c[r] = (i < N) ? cnt[i] : 0;
    s += c[r];
  }
  lds[t] = s;
  __syncthreads();
  for (int off = 1; off < 256; off <<= 1) {
    int v = 0;
    if (t >= off) v = lds[t - off];
    __syncthreads();
    if (t >= off) lds[t] += v;
    __syncthreads();
  }
  if (t == 255) base_sh = atomicAdd(total, lds[255]);
  __syncthreads();

  int run = base_sh + (t == 0 ? 0 : lds[t - 1]);
#pragma unroll
  for (int r = 0; r < 8; ++r) {
    int i = b0 + t * 8 + r;
    if (i < N) { start[i] = run; cur[i] = run; }
    run += c[r];
  }
}

__global__ __launch_bounds__(256) void reorder_kernel(
    const int* __restrict__ row, const int* __restrict__ col,
    const float* __restrict__ w, int* __restrict__ cur,
    int2* __restrict__ swcol, int E) {
  int e = blockIdx.x * 256 + threadIdx.x;
  if (e >= E) return;
  int pos = atomicAdd(&cur[row[e]], 1);
  swcol[pos] = make_int2(col[e], __float_as_int(w[e]));
}

// ---------------- y = bf16(x @ W^T), MFMA ----------------
// Block = 4 waves; block tile 64 rows x 128 cols. Wave: (wave&1) picks 32-row
// half, (wave>>1) picks 64-col half -> 2 mtiles x 4 ntiles of 16x16 per wave.
// B-frags (W) live in registers (64 VGPRs), loaded once; A-frags load straight
// from global (x has no reuse), fused fp32->bf16 cvt. No LDS.

__global__ __launch_bounds__(256) void gemm_mfma_kernel(
    const float* __restrict__ x, const float* __restrict__ W,
    ushort* __restrict__ y, int N) {
  const int tid = threadIdx.x;
  const int wave = tid >> 6, lane = tid & 63;
  const int m_half = wave & 1;
  const int n_half = wave >> 1;
  const int l16 = lane & 15, quad = lane >> 4;

  // B[k][n] = W[n][k]; lane holds n = base + l16, k = kb*32 + quad*8 + j.
  // j=0..7 contiguous in W's row n -> two float4 loads per frag.
  bf16x8 Bf[4][4];
  const float4* W4 = (const float4*)W;
#pragma unroll
  for (int nt = 0; nt < 4; ++nt) {
    int n = n_half * 64 + nt * 16 + l16;
#pragma unroll
    for (int kb = 0; kb < 4; ++kb) {
      int idx = (n * D + kb * 32 + quad * 8) >> 2;
      Bf[nt][kb] = pack_bf16x8(W4[idx], W4[idx + 1]);
    }
  }

  const float4* x4 = (const float4*)x;
  const int ntiles = (N + 63) >> 6;
  for (int tile = blockIdx.x; tile < ntiles; tile += gridDim.x) {
    const int row0 = tile * 64 + m_half * 32;
    f32x4 acc[2][4];
#pragma unroll
    for (int mt = 0; mt < 2; ++mt)
#pragma unroll
      for (int nt = 0; nt < 4; ++nt)
        acc[mt][nt] = (f32x4){0.f, 0.f, 0.f, 0.f};

#pragma unroll
    for (int kb = 0; kb < 4; ++kb) {
      const int k0 = kb * 32 + quad * 8;
      int m0 = row0 + l16;        if (m0 > N - 1) m0 = N - 1;   // tail-safe
      int m1 = row0 + 16 + l16;   if (m1 > N - 1) m1 = N - 1;
      int i0 = (m0 * D + k0) >> 2;
      int i1 = (m1 * D + k0) >> 2;
      float4 p0 = x4[i0], q0 = x4[i0 + 1];
      float4 p1 = x4[i1], q1 = x4[i1 + 1];
      bf16x8 a0 = pack_bf16x8(p0, q0);
      bf16x8 a1 = pack_bf16x8(p1, q1);
#pragma unroll
      for (int nt = 0; nt < 4; ++nt) {
        acc[0][nt] = __builtin_amdgcn_mfma_f32_16x16x32_bf16(a0, Bf[nt][kb], acc[0][nt], 0, 0, 0);
        acc[1][nt] = __builtin_amdgcn_mfma_f32_16x16x32_bf16(a1, Bf[nt][kb], acc[1][nt], 0, 0, 0);
      }
    }

    // D: col = base + l16, row = rbase + quad*4 + reg  (m89-verified layout)
#pragma unroll
    for (int mt = 0; mt < 2; ++mt) {
      int rbase = row0 + mt * 16 + quad * 4;
#pragma unroll
      for (int nt = 0; nt < 4; ++nt) {
        int col = n_half * 64 + nt * 16 + l16;
#pragma unroll
        for (int r = 0; r < 4; ++r) {
          int row = rbase + r;
          if (row < N) y[row * D + col] = (ushort)f2bf_rne(acc[mt][nt][r]);
        }
      }
    }
  }
}

// ---------------- gather: out[i] = b + sum_j w_j * y[col_j]  (y bf16) ----------------
// One wave per node; lane holds one dword = 2 bf16 cols (2*lane, 2*lane+1).

__global__ __launch_bounds__(256) void gather_agg_kernel(
    const ushort* __restrict__ y, const int* __restrict__ start,
    const int* __restrict__ cnt, const int2* __restrict__ swcol,
    const float* __restrict__ b, float* __restrict__ out, int N) {
  const int node = blockIdx.x * 4 + (threadIdx.x >> 6);
  const int lane = threadIdx.x & 63;
  if (node >= N) return;

  const unsigned* __restrict__ y1 = (const unsigned*)y;
  float2 acc = ((const float2*)b)[lane];

  const int s = start[node];
  const int t = s + cnt[node];
#pragma unroll 4
  for (int j = s; j < t; ++j) {
    int2 cw = swcol[j];                  // wave-uniform 8B broadcast
    float wg = __int_as_float(cw.y);
    unsigned v = y1[cw.x * 64 + lane];   // 256 B/edge coalesced gather
    float f0 = __uint_as_float(v << 16);
    float f1 = __uint_as_float(v & 0xffff0000u);
    acc.x += wg * f0;
    acc.y += wg * f1;
  }
  ((float2*)out)[node * 64 + lane] = acc;
}

// ---------------- launch ----------------

extern "C" void kernel_launch(void* const* d_in, const int* in_sizes, int n_in,
                              void* d_out, int out_size, void* d_ws, size_t ws_size,
                              hipStream_t stream) {
  const float* x    = (const float*)d_in[0];
  const int*   erow = (const int*)d_in[1];
  const int*   ecol = (const int*)d_in[2];
  const float* ew   = (const float*)d_in[3];
  const float* W    = (const float*)d_in[4];
  const float* b    = (const float*)d_in[5];
  float* out = (float*)d_out;

  const int N = in_sizes[0] / D;
  const int E = in_sizes[1];

  // Workspace layout
  char* ws = (char*)d_ws;
  ushort* y    = (ushort*)ws;                            // N*D bf16 (12.8 MB)
  int2*  swcol = (int2*)(ws + (size_t)N * D * 2);        // E int2 (6.4 MB), 8B-aligned
  int*   cnt   = (int*)(swcol + E);                      // N ints
  int*   total = cnt + N;                                // 1 int
  int*   start = total + 1;                              // N ints
  int*   cur   = start + N;                              // N ints

  const int eb = (E + 255) / 256;
  const int nb = (N + 1 + 255) / 256;

  zero_cnt_kernel<<<nb, 256, 0, stream>>>(cnt, N);       // zeroes cnt + total
  hist_kernel<<<eb, 256, 0, stream>>>(erow, cnt, E);
  assign_starts_kernel<<<(N + 2047) / 2048, 256, 0, stream>>>(cnt, start, cur, total, N);
  reorder_kernel<<<eb, 256, 0, stream>>>(erow, ecol, ew, cur, swcol, E);

  const int ntiles = (N + 63) >> 6;
  gemm_mfma_kernel<<<ntiles, 256, 0, stream>>>(x, W, y, N);

  gather_agg_kernel<<<(N + 3) / 4, 256, 0, stream>>>(y, start, cnt, swcol, b, out, N);
}